// Round 1
// baseline (570.977 us; speedup 1.0000x reference)
//
#include <hip/hip_runtime.h>
#include <stdint.h>

#define L_SZ 110
#define D_SZ 512
#define OUT_W 110
#define A_STRIDE 520   // bf16 elems per LDS A row (512 + 8 pad, keeps 16B align)
#define C_STRIDE 136   // bf16 elems per LDS C row (128 + 8 pad)
#define A_ROWS 112

typedef __attribute__((ext_vector_type(8))) __bf16 bf16x8;
typedef __attribute__((ext_vector_type(4))) __bf16 bf16x4;
typedef __attribute__((ext_vector_type(4))) float f32x4;

// Convert W (512x512 fp32, row-major [d][e]) to bf16 in workspace.
__global__ __launch_bounds__(256) void wconv_kernel(const float* __restrict__ W,
                                                    __bf16* __restrict__ wbf) {
    int idx = blockIdx.x * 256 + threadIdx.x;   // 65536 threads, 4 elems each
    float4 w = ((const float4*)W)[idx];
    bf16x4 o;
    o[0] = (__bf16)w.x; o[1] = (__bf16)w.y; o[2] = (__bf16)w.z; o[3] = (__bf16)w.w;
    ((bf16x4*)wbf)[idx] = o;
}

__global__ __launch_bounds__(256, 1) void edgeatt_kernel(
    const float* __restrict__ nf, const float* __restrict__ Wf,
    const __bf16* __restrict__ wbf, const int* __restrict__ tlenp,
    float* __restrict__ out, int use_wb)
{
    __shared__ __bf16 A_lds[A_ROWS * A_STRIDE];   // nf[b] as bf16 (A-operand both GEMMs)
    __shared__ __bf16 C_lds[A_ROWS * C_STRIDE];   // current 128-wide d-chunk of att

    const int b = blockIdx.x;
    const int tid = threadIdx.x;
    const int lane = tid & 63;
    const int wave = tid >> 6;
    const int l15 = lane & 15;
    const int quad = lane >> 4;

    int len = tlenp[b];
    if (len > L_SZ) len = L_SZ;
    if (len < 1) len = 1;
    const int T = (len + 15) >> 4;               // 16-tiles covering [0,len)

    const float* nfb = nf + (size_t)b * (L_SZ * D_SZ);
    float* outb = out + (size_t)b * (L_SZ * OUT_W);

    // ---- zero-fill the complement of the stored band window (disjoint from band stores) ----
    for (int j = tid; j < L_SZ; j += 256) {
        int tj = j >> 4;
        int lo = 0, hi = 0;
        if (j < 16 * T) {
            lo = (tj > 0) ? 16 * (tj - 1) : 0;
            int th = (tj + 2 < T) ? (tj + 2) : T;
            hi = 16 * th; if (hi > OUT_W) hi = OUT_W;
        }
        float* row = outb + (size_t)j * OUT_W;
        for (int l = 0; l < lo; ++l) row[l] = 0.0f;
        for (int l = hi; l < OUT_W; ++l) row[l] = 0.0f;
    }

    // ---- stage A = nf[b] rows [0,len) into LDS as bf16; zero-pad to tile boundary ----
    {
        int total4 = len * (D_SZ / 4);
        for (int idx = tid; idx < total4; idx += 256) {
            int row = idx >> 7;          // /128 float4s per row
            int c4 = idx & 127;
            float4 v = ((const float4*)nfb)[row * 128 + c4];
            bf16x4 o;
            o[0]=(__bf16)v.x; o[1]=(__bf16)v.y; o[2]=(__bf16)v.z; o[3]=(__bf16)v.w;
            *(bf16x4*)&A_lds[row * A_STRIDE + c4 * 4] = o;
        }
        int zr = 16 * T - len;
        if (zr > 0) {
            int per = A_STRIDE / 4;      // 130 bf16x4 per row (incl. pad)
            int totalz = zr * per;
            for (int idx = tid; idx < totalz; idx += 256) {
                int row = len + idx / per;
                int c4 = idx % per;
                bf16x4 z; z[0]=z[1]=z[2]=z[3]=(__bf16)0.0f;
                *(bf16x4*)&A_lds[row * A_STRIDE + c4 * 4] = z;
            }
        }
    }
    __syncthreads();

    // wave grid: 2x2 over (M-tiles, N-tiles) for GEMM1
    const int wm = wave >> 1, wn = wave & 1;
    const int h = (T + 1) >> 1;
    const int mt_lo = (wm == 0) ? 0 : h;
    const int nmt = ((wm == 0) ? h : T) - mt_lo;   // 0..4 M-tiles for this wave

    const f32x4 fzero = {0.f, 0.f, 0.f, 0.f};
    // S band accumulators: tj = wave + 4*i, tl = tj-1+t
    f32x4 accS[2][3];
    #pragma unroll
    for (int i = 0; i < 2; ++i)
        #pragma unroll
        for (int t = 0; t < 3; ++t) accS[i][t] = fzero;

    for (int c = 0; c < 4; ++c) {
        const int d0 = c * 128;
        f32x4 acc1[4][4];
        #pragma unroll
        for (int mi = 0; mi < 4; ++mi)
            #pragma unroll
            for (int ni = 0; ni < 4; ++ni) acc1[mi][ni] = fzero;

        // ---- GEMM1: C[l, d0..d0+127] = A @ W^T (K = 512) ----
        if (nmt > 0) {
            for (int k0 = 0; k0 < D_SZ; k0 += 32) {
                bf16x8 afrag[4], bfrag[4];
                #pragma unroll
                for (int ni = 0; ni < 4; ++ni) {
                    int d = d0 + (wn * 4 + ni) * 16 + l15;
                    if (use_wb) {
                        bfrag[ni] = *(const bf16x8*)&wbf[(size_t)d * D_SZ + k0 + quad * 8];
                    } else {
                        const float* wp = &Wf[(size_t)d * D_SZ + k0 + quad * 8];
                        float4 w0 = *(const float4*)wp;
                        float4 w1 = *(const float4*)(wp + 4);
                        bf16x8 bb;
                        bb[0]=(__bf16)w0.x; bb[1]=(__bf16)w0.y; bb[2]=(__bf16)w0.z; bb[3]=(__bf16)w0.w;
                        bb[4]=(__bf16)w1.x; bb[5]=(__bf16)w1.y; bb[6]=(__bf16)w1.z; bb[7]=(__bf16)w1.w;
                        bfrag[ni] = bb;
                    }
                }
                #pragma unroll
                for (int mi = 0; mi < 4; ++mi) {
                    if (mi < nmt) {
                        int row = (mt_lo + mi) * 16 + l15;
                        afrag[mi] = *(const bf16x8*)&A_lds[row * A_STRIDE + k0 + quad * 8];
                    }
                }
                #pragma unroll
                for (int mi = 0; mi < 4; ++mi) {
                    if (mi < nmt) {
                        #pragma unroll
                        for (int ni = 0; ni < 4; ++ni)
                            acc1[mi][ni] = __builtin_amdgcn_mfma_f32_16x16x32_bf16(
                                afrag[mi], bfrag[ni], acc1[mi][ni], 0, 0, 0);
                    }
                }
            }
        }
        __syncthreads();   // prior GEMM2 readers of C_lds are done

        // ---- write C chunk to LDS as bf16 (C/D layout: row = quad*4+reg, col = lane&15) ----
        #pragma unroll
        for (int mi = 0; mi < 4; ++mi) {
            if (mi < nmt) {
                int lbase = (mt_lo + mi) * 16 + quad * 4;
                #pragma unroll
                for (int ni = 0; ni < 4; ++ni) {
                    int dloc = (wn * 4 + ni) * 16 + l15;
                    #pragma unroll
                    for (int r = 0; r < 4; ++r)
                        C_lds[(lbase + r) * C_STRIDE + dloc] = (__bf16)acc1[mi][ni][r];
                }
            }
        }
        __syncthreads();

        // ---- GEMM2: S[j,l] += A[:, d-chunk] @ C_chunk^T, band tiles only ----
        for (int kk = 0; kk < 128; kk += 32) {
            #pragma unroll
            for (int i = 0; i < 2; ++i) {
                int tj = wave + 4 * i;
                if (tj < T) {
                    bf16x8 aj = *(const bf16x8*)&A_lds[(tj * 16 + l15) * A_STRIDE + d0 + kk + quad * 8];
                    #pragma unroll
                    for (int t = 0; t < 3; ++t) {
                        int tl = tj - 1 + t;
                        if (tl >= 0 && tl < T) {
                            bf16x8 bj = *(const bf16x8*)&C_lds[(tl * 16 + l15) * C_STRIDE + kk + quad * 8];
                            accS[i][t] = __builtin_amdgcn_mfma_f32_16x16x32_bf16(
                                aj, bj, accS[i][t], 0, 0, 0);
                        }
                    }
                }
            }
        }
        __syncthreads();
    }

    // ---- epilogue: masked softmax over l within each row j, store band window ----
    #pragma unroll
    for (int i = 0; i < 2; ++i) {
        int tj = wave + 4 * i;
        if (tj >= T) continue;           // wave-uniform
        #pragma unroll
        for (int r = 0; r < 4; ++r) {
            int j = tj * 16 + quad * 4 + r;   // same j for all 16 lanes of the quad
            float v[3]; bool mk[3];
            float vmax = -3.0e38f;
            #pragma unroll
            for (int t = 0; t < 3; ++t) {
                int tl = tj - 1 + t;
                int l = tl * 16 + l15;
                bool in = (tl >= 0) && (tl < T) && (j < len) && (l < len)
                          && (l >= j - 10) && (l <= j + 10);
                float val = in ? accS[i][t][r] : -3.0e38f;
                mk[t] = in; v[t] = val;
                vmax = fmaxf(vmax, val);
            }
            #pragma unroll
            for (int s = 1; s < 16; s <<= 1)
                vmax = fmaxf(vmax, __shfl_xor(vmax, s, 16));
            float e[3]; float esum = 0.f;
            #pragma unroll
            for (int t = 0; t < 3; ++t) {
                e[t] = mk[t] ? __expf(v[t] - vmax) : 0.f;
                esum += e[t];
            }
            #pragma unroll
            for (int s = 1; s < 16; s <<= 1)
                esum += __shfl_xor(esum, s, 16);
            float inv = (esum > 0.f) ? (1.0f / esum) : 0.f;
            if (j < OUT_W) {
                #pragma unroll
                for (int t = 0; t < 3; ++t) {
                    int tl = tj - 1 + t;
                    if (tl >= 0 && tl < T) {
                        int l = tl * 16 + l15;
                        if (l < OUT_W) outb[(size_t)j * OUT_W + l] = e[t] * inv;
                    }
                }
            }
        }
    }
}

extern "C" void kernel_launch(void* const* d_in, const int* in_sizes, int n_in,
                              void* d_out, int out_size, void* d_ws, size_t ws_size,
                              hipStream_t stream) {
    const float* nf = (const float*)d_in[0];
    const float* W  = (const float*)d_in[1];
    const int* tl   = (const int*)d_in[2];
    float* out      = (float*)d_out;
    __bf16* wbf     = (__bf16*)d_ws;

    int use_wb = (ws_size >= (size_t)D_SZ * D_SZ * sizeof(__bf16)) ? 1 : 0;
    if (use_wb) {
        hipLaunchKernelGGL(wconv_kernel, dim3(256), dim3(256), 0, stream, W, wbf);
    }
    hipLaunchKernelGGL(edgeatt_kernel, dim3(1024), dim3(256), 0, stream,
                       nf, W, wbf, tl, out, use_wb);
}

// Round 2
// 545.917 us; speedup vs baseline: 1.0459x; 1.0459x over previous
//
#include <hip/hip_runtime.h>
#include <stdint.h>

#define L_SZ 110
#define D_SZ 512
#define OUT_W 110
#define A_STRIDE 520   // bf16 elems per LDS A row (512 + 8 pad, 16B-aligned rows)
#define C_STRIDE 136   // bf16 elems per LDS C row (128 + 8 pad, 16B-aligned rows)
#define A_ROWS 112
#define ATT_ROWS 112

typedef __attribute__((ext_vector_type(8))) __bf16 bf16x8;
typedef __attribute__((ext_vector_type(4))) __bf16 bf16x4;
typedef __attribute__((ext_vector_type(4))) float f32x4;

// Convert W (512x512 fp32, row-major [d][e]) to bf16 in workspace.
__global__ __launch_bounds__(256) void wconv_kernel(const float* __restrict__ W,
                                                    __bf16* __restrict__ wbf) {
    int idx = blockIdx.x * 256 + threadIdx.x;   // 65536 threads, 4 elems each
    float4 w = ((const float4*)W)[idx];
    bf16x4 o;
    o[0] = (__bf16)w.x; o[1] = (__bf16)w.y; o[2] = (__bf16)w.z; o[3] = (__bf16)w.w;
    ((bf16x4*)wbf)[idx] = o;
}

// ---------------- K1: att[b,l,d] = sum_e W[d,e] * nf[b,l,e], bf16 out ----------------
// One block per batch. 8 waves, wave w owns d-cols [w*64, w*64+64). M = all T tiles.
// nf read once (rows < len). K-panels of 128 software-pipelined through registers.
__global__ __launch_bounds__(512, 2) void att_gemm_kernel(
    const float* __restrict__ nf, const __bf16* __restrict__ wbf,
    const int* __restrict__ tlenp, __bf16* __restrict__ attws)
{
    __shared__ __bf16 A_lds[A_ROWS * A_STRIDE];   // 116,480 B; epilogue reuses it

    const int b = blockIdx.x;
    const int tid = threadIdx.x;
    const int lane = tid & 63;
    const int wave = tid >> 6;
    const int l15 = lane & 15;
    const int quad = lane >> 4;

    int len = tlenp[b];
    if (len > L_SZ) len = L_SZ;
    if (len < 1) len = 1;
    const int T = (len + 15) >> 4;

    const float* nfb = nf + (size_t)b * (L_SZ * D_SZ);

    // staging map: per panel 112 rows x 32 float4; thread covers 7 float4s
    float4 buf[7];
    auto issue_panel = [&](int p) {
        #pragma unroll
        for (int s = 0; s < 7; ++s) {
            int idx = tid + (s << 9);
            int row = idx >> 5, c4 = idx & 31;
            float4 z = {0.f, 0.f, 0.f, 0.f};
            buf[s] = (row < len) ? ((const float4*)nfb)[row * 128 + (p << 5) + c4] : z;
        }
    };
    auto write_panel = [&](int p) {
        #pragma unroll
        for (int s = 0; s < 7; ++s) {
            int idx = tid + (s << 9);
            int row = idx >> 5, c4 = idx & 31;
            bf16x4 o;
            o[0] = (__bf16)buf[s].x; o[1] = (__bf16)buf[s].y;
            o[2] = (__bf16)buf[s].z; o[3] = (__bf16)buf[s].w;
            *(bf16x4*)&A_lds[row * A_STRIDE + (p << 7) + (c4 << 2)] = o;
        }
    };

    f32x4 acc[7][4];
    const f32x4 fz = {0.f, 0.f, 0.f, 0.f};
    #pragma unroll
    for (int mt = 0; mt < 7; ++mt)
        #pragma unroll
        for (int ni = 0; ni < 4; ++ni) acc[mt][ni] = fz;

    issue_panel(0);
    write_panel(0);

    for (int p = 0; p < 4; ++p) {
        if (p < 3) issue_panel(p + 1);      // loads in flight under MFMA below
        __syncthreads();                    // panel p visible to all waves
        #pragma unroll
        for (int ks = 0; ks < 4; ++ks) {
            const int k0 = (p << 7) + (ks << 5);
            bf16x8 bfr[4];
            #pragma unroll
            for (int ni = 0; ni < 4; ++ni) {
                int d = (wave << 6) + (ni << 4) + l15;
                bfr[ni] = *(const bf16x8*)&wbf[(size_t)d * D_SZ + k0 + (quad << 3)];
            }
            bf16x8 afr[7];
            #pragma unroll
            for (int mt = 0; mt < 7; ++mt)
                if (mt < T)
                    afr[mt] = *(const bf16x8*)&A_lds[((mt << 4) + l15) * A_STRIDE + k0 + (quad << 3)];
            #pragma unroll
            for (int mt = 0; mt < 7; ++mt)
                if (mt < T)
                    #pragma unroll
                    for (int ni = 0; ni < 4; ++ni)
                        acc[mt][ni] = __builtin_amdgcn_mfma_f32_16x16x32_bf16(
                            afr[mt], bfr[ni], acc[mt][ni], 0, 0, 0);
        }
        if (p < 3) write_panel(p + 1);      // own columns; published by next barrier
    }
    __syncthreads();

    // epilogue: per 128-col chunk, stage bf16 into LDS (C/D layout transpose),
    // then coalesced bf16x8 stores to attws.
    __bf16* Cst = (__bf16*)A_lds;
    const int nrow = T << 4;
    for (int cc = 0; cc < 4; ++cc) {
        if ((wave >> 1) == cc) {
            const int nbase = (wave & 1) << 6;
            #pragma unroll
            for (int mt = 0; mt < 7; ++mt)
                if (mt < T) {
                    int rbase = (mt << 4) + (quad << 2);
                    #pragma unroll
                    for (int ni = 0; ni < 4; ++ni) {
                        int dl = nbase + (ni << 4) + l15;
                        #pragma unroll
                        for (int r = 0; r < 4; ++r)
                            Cst[(rbase + r) * C_STRIDE + dl] = (__bf16)acc[mt][ni][r];
                    }
                }
        }
        __syncthreads();
        for (int idx = tid; idx < (nrow << 4); idx += 512) {
            int row = idx >> 4, c8 = idx & 15;
            bf16x8 v = *(const bf16x8*)&Cst[row * C_STRIDE + (c8 << 3)];
            *(bf16x8*)&attws[((size_t)b * ATT_ROWS + row) * D_SZ + (cc << 7) + (c8 << 3)] = v;
        }
        __syncthreads();
    }
}

// ---------------- K2: banded scores + masked softmax, no LDS, no barriers ----------------
__global__ __launch_bounds__(256) void band_kernel(
    const float* __restrict__ nf, const __bf16* __restrict__ attws,
    const int* __restrict__ tlenp, float* __restrict__ out)
{
    const int b = blockIdx.x;
    const int tid = threadIdx.x;
    const int lane = tid & 63;
    const int wave = tid >> 6;
    const int l15 = lane & 15;
    const int quad = lane >> 4;

    int len = tlenp[b];
    if (len > L_SZ) len = L_SZ;
    if (len < 1) len = 1;
    const int T = (len + 15) >> 4;

    const float* nfb = nf + (size_t)b * (L_SZ * D_SZ);
    float* outb = out + (size_t)b * (L_SZ * OUT_W);

    // zero-fill the complement of the stored band window
    for (int j = tid; j < L_SZ; j += 256) {
        int tj = j >> 4;
        int lo = 0, hi = 0;
        if (j < 16 * T) {
            lo = (tj > 0) ? 16 * (tj - 1) : 0;
            int th = (tj + 2 < T) ? (tj + 2) : T;
            hi = 16 * th; if (hi > OUT_W) hi = OUT_W;
        }
        float* row = outb + (size_t)j * OUT_W;
        for (int l = 0; l < lo; ++l) row[l] = 0.0f;
        for (int l = hi; l < OUT_W; ++l) row[l] = 0.0f;
    }

    const f32x4 fz = {0.f, 0.f, 0.f, 0.f};
    f32x4 accS[2][3];
    #pragma unroll
    for (int i = 0; i < 2; ++i)
        #pragma unroll
        for (int t = 0; t < 3; ++t) accS[i][t] = fz;

    #pragma unroll
    for (int i = 0; i < 2; ++i) {
        const int tj = wave + (i << 2);
        if (tj < T) {
            int jr = (tj << 4) + l15;
            if (jr > L_SZ - 1) jr = L_SZ - 1;       // keep rows 110/111 in-bounds; discarded later
            const float* ap0 = &nfb[(size_t)jr * D_SZ];
            for (int k0 = 0; k0 < D_SZ; k0 += 32) {
                float4 a0 = *(const float4*)(ap0 + k0 + (quad << 3));
                float4 a1 = *(const float4*)(ap0 + k0 + (quad << 3) + 4);
                bf16x8 af;
                af[0] = (__bf16)a0.x; af[1] = (__bf16)a0.y;
                af[2] = (__bf16)a0.z; af[3] = (__bf16)a0.w;
                af[4] = (__bf16)a1.x; af[5] = (__bf16)a1.y;
                af[6] = (__bf16)a1.z; af[7] = (__bf16)a1.w;
                #pragma unroll
                for (int t = 0; t < 3; ++t) {
                    int tl = tj - 1 + t;
                    if (tl >= 0 && tl < T) {
                        bf16x8 bfr = *(const bf16x8*)&attws[((size_t)b * ATT_ROWS + (tl << 4) + l15) * D_SZ + k0 + (quad << 3)];
                        accS[i][t] = __builtin_amdgcn_mfma_f32_16x16x32_bf16(
                            af, bfr, accS[i][t], 0, 0, 0);
                    }
                }
            }
        }
    }

    // masked softmax over l within each row j, store band window
    #pragma unroll
    for (int i = 0; i < 2; ++i) {
        int tj = wave + 4 * i;
        if (tj >= T) continue;           // wave-uniform
        #pragma unroll
        for (int r = 0; r < 4; ++r) {
            int j = tj * 16 + quad * 4 + r;
            float v[3]; bool mk[3];
            float vmax = -3.0e38f;
            #pragma unroll
            for (int t = 0; t < 3; ++t) {
                int tl = tj - 1 + t;
                int l = tl * 16 + l15;
                bool in = (tl >= 0) && (tl < T) && (j < len) && (l < len)
                          && (l >= j - 10) && (l <= j + 10);
                float val = in ? accS[i][t][r] : -3.0e38f;
                mk[t] = in; v[t] = val;
                vmax = fmaxf(vmax, val);
            }
            #pragma unroll
            for (int s = 1; s < 16; s <<= 1)
                vmax = fmaxf(vmax, __shfl_xor(vmax, s, 16));
            float e[3]; float esum = 0.f;
            #pragma unroll
            for (int t = 0; t < 3; ++t) {
                e[t] = mk[t] ? __expf(v[t] - vmax) : 0.f;
                esum += e[t];
            }
            #pragma unroll
            for (int s = 1; s < 16; s <<= 1)
                esum += __shfl_xor(esum, s, 16);
            float inv = (esum > 0.f) ? (1.0f / esum) : 0.f;
            if (j < OUT_W) {
                #pragma unroll
                for (int t = 0; t < 3; ++t) {
                    int tl = tj - 1 + t;
                    if (tl >= 0 && tl < T) {
                        int l = tl * 16 + l15;
                        if (l < OUT_W) outb[(size_t)j * OUT_W + l] = e[t] * inv;
                    }
                }
            }
        }
    }
}

// ---------------- fallback: round-1 fused kernel (passes, 327 us) ----------------
__global__ __launch_bounds__(256, 1) void edgeatt_kernel(
    const float* __restrict__ nf, const float* __restrict__ Wf,
    const __bf16* __restrict__ wbf, const int* __restrict__ tlenp,
    float* __restrict__ out, int use_wb)
{
    __shared__ __bf16 A_lds[A_ROWS * A_STRIDE];
    __shared__ __bf16 C_lds[A_ROWS * C_STRIDE];

    const int b = blockIdx.x;
    const int tid = threadIdx.x;
    const int lane = tid & 63;
    const int wave = tid >> 6;
    const int l15 = lane & 15;
    const int quad = lane >> 4;

    int len = tlenp[b];
    if (len > L_SZ) len = L_SZ;
    if (len < 1) len = 1;
    const int T = (len + 15) >> 4;

    const float* nfb = nf + (size_t)b * (L_SZ * D_SZ);
    float* outb = out + (size_t)b * (L_SZ * OUT_W);

    for (int j = tid; j < L_SZ; j += 256) {
        int tj = j >> 4;
        int lo = 0, hi = 0;
        if (j < 16 * T) {
            lo = (tj > 0) ? 16 * (tj - 1) : 0;
            int th = (tj + 2 < T) ? (tj + 2) : T;
            hi = 16 * th; if (hi > OUT_W) hi = OUT_W;
        }
        float* row = outb + (size_t)j * OUT_W;
        for (int l = 0; l < lo; ++l) row[l] = 0.0f;
        for (int l = hi; l < OUT_W; ++l) row[l] = 0.0f;
    }

    {
        int total4 = len * (D_SZ / 4);
        for (int idx = tid; idx < total4; idx += 256) {
            int row = idx >> 7;
            int c4 = idx & 127;
            float4 v = ((const float4*)nfb)[row * 128 + c4];
            bf16x4 o;
            o[0]=(__bf16)v.x; o[1]=(__bf16)v.y; o[2]=(__bf16)v.z; o[3]=(__bf16)v.w;
            *(bf16x4*)&A_lds[row * A_STRIDE + c4 * 4] = o;
        }
        int zr = 16 * T - len;
        if (zr > 0) {
            int per = A_STRIDE / 4;
            int totalz = zr * per;
            for (int idx = tid; idx < totalz; idx += 256) {
                int row = len + idx / per;
                int c4 = idx % per;
                bf16x4 z; z[0]=z[1]=z[2]=z[3]=(__bf16)0.0f;
                *(bf16x4*)&A_lds[row * A_STRIDE + c4 * 4] = z;
            }
        }
    }
    __syncthreads();

    const int wm = wave >> 1, wn = wave & 1;
    const int h = (T + 1) >> 1;
    const int mt_lo = (wm == 0) ? 0 : h;
    const int nmt = ((wm == 0) ? h : T) - mt_lo;

    const f32x4 fzero = {0.f, 0.f, 0.f, 0.f};
    f32x4 accS[2][3];
    #pragma unroll
    for (int i = 0; i < 2; ++i)
        #pragma unroll
        for (int t = 0; t < 3; ++t) accS[i][t] = fzero;

    for (int c = 0; c < 4; ++c) {
        const int d0 = c * 128;
        f32x4 acc1[4][4];
        #pragma unroll
        for (int mi = 0; mi < 4; ++mi)
            #pragma unroll
            for (int ni = 0; ni < 4; ++ni) acc1[mi][ni] = fzero;

        if (nmt > 0) {
            for (int k0 = 0; k0 < D_SZ; k0 += 32) {
                bf16x8 afrag[4], bfrag[4];
                #pragma unroll
                for (int ni = 0; ni < 4; ++ni) {
                    int d = d0 + (wn * 4 + ni) * 16 + l15;
                    if (use_wb) {
                        bfrag[ni] = *(const bf16x8*)&wbf[(size_t)d * D_SZ + k0 + quad * 8];
                    } else {
                        const float* wp = &Wf[(size_t)d * D_SZ + k0 + quad * 8];
                        float4 w0 = *(const float4*)wp;
                        float4 w1 = *(const float4*)(wp + 4);
                        bf16x8 bb;
                        bb[0]=(__bf16)w0.x; bb[1]=(__bf16)w0.y; bb[2]=(__bf16)w0.z; bb[3]=(__bf16)w0.w;
                        bb[4]=(__bf16)w1.x; bb[5]=(__bf16)w1.y; bb[6]=(__bf16)w1.z; bb[7]=(__bf16)w1.w;
                        bfrag[ni] = bb;
                    }
                }
                #pragma unroll
                for (int mi = 0; mi < 4; ++mi) {
                    if (mi < nmt) {
                        int row = (mt_lo + mi) * 16 + l15;
                        afrag[mi] = *(const bf16x8*)&A_lds[row * A_STRIDE + k0 + quad * 8];
                    }
                }
                #pragma unroll
                for (int mi = 0; mi < 4; ++mi) {
                    if (mi < nmt) {
                        #pragma unroll
                        for (int ni = 0; ni < 4; ++ni)
                            acc1[mi][ni] = __builtin_amdgcn_mfma_f32_16x16x32_bf16(
                                afrag[mi], bfrag[ni], acc1[mi][ni], 0, 0, 0);
                    }
                }
            }
        }
        __syncthreads();

        #pragma unroll
        for (int mi = 0; mi < 4; ++mi) {
            if (mi < nmt) {
                int lbase = (mt_lo + mi) * 16 + quad * 4;
                #pragma unroll
                for (int ni = 0; ni < 4; ++ni) {
                    int dloc = (wn * 4 + ni) * 16 + l15;
                    #pragma unroll
                    for (int r = 0; r < 4; ++r)
                        C_lds[(lbase + r) * C_STRIDE + dloc] = (__bf16)acc1[mi][ni][r];
                }
            }
        }
        __syncthreads();

        for (int kk = 0; kk < 128; kk += 32) {
            #pragma unroll
            for (int i = 0; i < 2; ++i) {
                int tj = wave + 4 * i;
                if (tj < T) {
                    bf16x8 aj = *(const bf16x8*)&A_lds[(tj * 16 + l15) * A_STRIDE + d0 + kk + quad * 8];
                    #pragma unroll
                    for (int t = 0; t < 3; ++t) {
                        int tl = tj - 1 + t;
                        if (tl >= 0 && tl < T) {
                            bf16x8 bj = *(const bf16x8*)&C_lds[(tl * 16 + l15) * C_STRIDE + kk + quad * 8];
                            accS[i][t] = __builtin_amdgcn_mfma_f32_16x16x32_bf16(
                                aj, bj, accS[i][t], 0, 0, 0);
                        }
                    }
                }
            }
        }
        __syncthreads();
    }

    #pragma unroll
    for (int i = 0; i < 2; ++i) {
        int tj = wave + 4 * i;
        if (tj >= T) continue;
        #pragma unroll
        for (int r = 0; r < 4; ++r) {
            int j = tj * 16 + quad * 4 + r;
            float v[3]; bool mk[3];
            float vmax = -3.0e38f;
            #pragma unroll
            for (int t = 0; t < 3; ++t) {
                int tl = tj - 1 + t;
                int l = tl * 16 + l15;
                bool in = (tl >= 0) && (tl < T) && (j < len) && (l < len)
                          && (l >= j - 10) && (l <= j + 10);
                float val = in ? accS[i][t][r] : -3.0e38f;
                mk[t] = in; v[t] = val;
                vmax = fmaxf(vmax, val);
            }
            #pragma unroll
            for (int s = 1; s < 16; s <<= 1)
                vmax = fmaxf(vmax, __shfl_xor(vmax, s, 16));
            float e[3]; float esum = 0.f;
            #pragma unroll
            for (int t = 0; t < 3; ++t) {
                e[t] = mk[t] ? __expf(v[t] - vmax) : 0.f;
                esum += e[t];
            }
            #pragma unroll
            for (int s = 1; s < 16; s <<= 1)
                esum += __shfl_xor(esum, s, 16);
            float inv = (esum > 0.f) ? (1.0f / esum) : 0.f;
            if (j < OUT_W) {
                #pragma unroll
                for (int t = 0; t < 3; ++t) {
                    int tl = tj - 1 + t;
                    if (tl >= 0 && tl < T) {
                        int l = tl * 16 + l15;
                        if (l < OUT_W) outb[(size_t)j * OUT_W + l] = e[t] * inv;
                    }
                }
            }
        }
    }
}

extern "C" void kernel_launch(void* const* d_in, const int* in_sizes, int n_in,
                              void* d_out, int out_size, void* d_ws, size_t ws_size,
                              hipStream_t stream) {
    const float* nf = (const float*)d_in[0];
    const float* W  = (const float*)d_in[1];
    const int* tl   = (const int*)d_in[2];
    float* out      = (float*)d_out;
    __bf16* wbf     = (__bf16*)d_ws;
    const int B = in_sizes[2];

    const size_t wb_bytes  = (size_t)D_SZ * D_SZ * sizeof(__bf16);
    const size_t att_bytes = (size_t)B * ATT_ROWS * D_SZ * sizeof(__bf16);
    const int use_wb = (ws_size >= wb_bytes) ? 1 : 0;
    const int fast   = (use_wb && ws_size >= wb_bytes + att_bytes) ? 1 : 0;

    if (use_wb) {
        hipLaunchKernelGGL(wconv_kernel, dim3(256), dim3(256), 0, stream, W, wbf);
    }
    if (fast) {
        __bf16* attws = (__bf16*)((char*)d_ws + wb_bytes);
        hipLaunchKernelGGL(att_gemm_kernel, dim3(B), dim3(512), 0, stream, nf, wbf, tl, attws);
        hipLaunchKernelGGL(band_kernel, dim3(B), dim3(256), 0, stream, nf, attws, tl, out);
    } else {
        hipLaunchKernelGGL(edgeatt_kernel, dim3(B), dim3(256), 0, stream,
                           nf, W, wbf, tl, out, use_wb);
    }
}